// Round 1
// baseline (288.719 us; speedup 1.0000x reference)
//
#include <hip/hip_runtime.h>
#include <hip/hip_bf16.h>

// Problem constants: B=4, S=2048, D=512, H=8, DK=64
// ws layout (bytes):
//   Xb    @ 0        : 8192*512 bf16        = 8388608
//   Wqkv  @ 8388608  : 1536*512 bf16        = 1572864   (BT: row n = which*512+h*64+dk, col k=d)
//   WoT   @ 9961472  : 512*512 bf16         = 524288    (row d, col c=dk*8+h)
//   Qb    @ 10485760 : 32*2048*64 bf16      = 8388608   ([bh][s][dk])
//   Kb    @ 18874368 : 8388608                          ([bh][s][dk])
//   VTb   @ 27262976 : 8388608                          ([bh][dk][s])
//   Oc    @ 35651584 : 8388608                          ([b][s][dk*8+h] concat layout)
// total 44040192 bytes

typedef __bf16 bf16;
typedef __bf16 bf16x8 __attribute__((ext_vector_type(8)));
typedef __bf16 bf16x4 __attribute__((ext_vector_type(4)));
typedef float  f32x4  __attribute__((ext_vector_type(4)));

#define AS1 __attribute__((address_space(1)))
#define AS3 __attribute__((address_space(3)))

__device__ __forceinline__ void async_lds16(const void* gsrc, void* ldst) {
  __builtin_amdgcn_global_load_lds((AS1 const void*)gsrc, (AS3 void*)ldst, 16, 0, 0);
}

// ---------------- converters ----------------

__global__ __launch_bounds__(256) void k_cvt_x(const float4* __restrict__ X,
                                               bf16x4* __restrict__ Xb) {
  int i = blockIdx.x * 256 + threadIdx.x;       // exactly 4194304/4 threads
  float4 v = X[i];
  bf16x4 o = { (bf16)v.x, (bf16)v.y, (bf16)v.z, (bf16)v.w };
  Xb[i] = o;
}

__global__ __launch_bounds__(256) void k_build_wqkv(const float* __restrict__ Wq,
                                                    const float* __restrict__ Wk,
                                                    const float* __restrict__ Wv,
                                                    bf16* __restrict__ BT) {
  int idx = blockIdx.x * 256 + threadIdx.x;     // < 1536*512
  int n = idx >> 9, d = idx & 511;
  int which = n >> 9, h = (n >> 6) & 7, dk = n & 63;
  const float* W = (which == 0) ? Wq : ((which == 1) ? Wk : Wv);
  BT[idx] = (bf16)W[((h << 9) + d) * 64 + dk];
}

__global__ __launch_bounds__(256) void k_build_wo(const float* __restrict__ Wo,
                                                  bf16* __restrict__ WoT) {
  int idx = blockIdx.x * 256 + threadIdx.x;     // < 512*512
  int d = idx >> 9, c = idx & 511;
  WoT[idx] = (bf16)Wo[(c << 9) + d];
}

// ---------------- GEMM mainloop (128x128 tile, BK=32, 4 waves) ----------------
// A row-major [M][K] bf16, BT row-major [N][K] bf16. acc[am][bn] = 16x16 frags.

__device__ __forceinline__ void gemm_tile(const bf16* __restrict__ A,
                                          const bf16* __restrict__ BT,
                                          int K, int m0, int n0,
                                          char* sm, f32x4 acc[4][4]) {
  const int tid = threadIdx.x;
  const int lane = tid & 63, w = tid >> 6;
  const int wm = w >> 1, wn = w & 1;
  const int lr = lane & 15, lg = lane >> 4;
  for (int k0 = 0; k0 < K; k0 += 32) {
    __syncthreads();   // previous iter's LDS reads complete before overwrite
    #pragma unroll
    for (int i = 0; i < 2; ++i) {
      int off16 = i * 256 + tid;               // 16B units into 8KB tile
      int row   = off16 >> 2;                  // 64B per row (32 bf16)
      int colb  = (off16 & 3) << 4;
      const char* srcA = (const char*)(A  + (m0 + row) * K + k0) + colb;
      const char* srcB = (const char*)(BT + (n0 + row) * K + k0) + colb;
      async_lds16(srcA, sm +        (i * 256 + w * 64) * 16);
      async_lds16(srcB, sm + 8192 + (i * 256 + w * 64) * 16);
    }
    __syncthreads();   // drains vmcnt (global_load_lds) per barrier semantics
    bf16x8 af[4], bfr[4];
    #pragma unroll
    for (int t = 0; t < 4; ++t) {
      af[t]  = *(const bf16x8*)(sm +        ((wm * 64 + t * 16 + lr) * 32 + 8 * lg) * 2);
      bfr[t] = *(const bf16x8*)(sm + 8192 + ((wn * 64 + t * 16 + lr) * 32 + 8 * lg) * 2);
    }
    #pragma unroll
    for (int am = 0; am < 4; ++am)
      #pragma unroll
      for (int bn = 0; bn < 4; ++bn)
        acc[am][bn] = __builtin_amdgcn_mfma_f32_16x16x32_bf16(af[am], bfr[bn], acc[am][bn], 0, 0, 0);
  }
}

// QKV projection: scatter epilogue into Q [bh][s][dk], K [bh][s][dk], V^T [bh][dk][s]
__global__ __launch_bounds__(256) void k_gemm_qkv(const bf16* __restrict__ A,
                                                  const bf16* __restrict__ BT,
                                                  bf16* __restrict__ Qb,
                                                  bf16* __restrict__ Kb,
                                                  bf16* __restrict__ VTb) {
  __shared__ char sm[16384];
  const int m0 = blockIdx.y * 128, n0 = blockIdx.x * 128;
  f32x4 acc[4][4];
  #pragma unroll
  for (int a = 0; a < 4; ++a)
    #pragma unroll
    for (int b = 0; b < 4; ++b) { f32x4 z = {0.f,0.f,0.f,0.f}; acc[a][b] = z; }
  gemm_tile(A, BT, 512, m0, n0, sm, acc);
  const int lane = threadIdx.x & 63, w = threadIdx.x >> 6;
  const int wm = w >> 1, wn = w & 1, lr = lane & 15, lg = lane >> 4;
  #pragma unroll
  for (int am = 0; am < 4; ++am)
    #pragma unroll
    for (int bn = 0; bn < 4; ++bn)
      #pragma unroll
      for (int r = 0; r < 4; ++r) {
        int m = m0 + wm * 64 + am * 16 + 4 * lg + r;
        int n = n0 + wn * 64 + bn * 16 + lr;
        int b = m >> 11, s = m & 2047;
        int which = n >> 9, h = (n >> 6) & 7, dk = n & 63;
        int bh = (b << 3) + h;
        bf16 v = (bf16)acc[am][bn][r];
        if (which == 0)      Qb[((bh << 11) + s) * 64 + dk] = v;
        else if (which == 1) Kb[((bh << 11) + s) * 64 + dk] = v;
        else                 VTb[((bh << 6) + dk) * 2048 + s] = v;
      }
}

// Output projection: C fp32 straight to d_out
__global__ __launch_bounds__(256) void k_gemm_out(const bf16* __restrict__ A,
                                                  const bf16* __restrict__ BT,
                                                  float* __restrict__ C) {
  __shared__ char sm[16384];
  const int m0 = blockIdx.y * 128, n0 = blockIdx.x * 128;
  f32x4 acc[4][4];
  #pragma unroll
  for (int a = 0; a < 4; ++a)
    #pragma unroll
    for (int b = 0; b < 4; ++b) { f32x4 z = {0.f,0.f,0.f,0.f}; acc[a][b] = z; }
  gemm_tile(A, BT, 512, m0, n0, sm, acc);
  const int lane = threadIdx.x & 63, w = threadIdx.x >> 6;
  const int wm = w >> 1, wn = w & 1, lr = lane & 15, lg = lane >> 4;
  #pragma unroll
  for (int am = 0; am < 4; ++am)
    #pragma unroll
    for (int bn = 0; bn < 4; ++bn)
      #pragma unroll
      for (int r = 0; r < 4; ++r) {
        int m = m0 + wm * 64 + am * 16 + 4 * lg + r;
        int n = n0 + wn * 64 + bn * 16 + lr;
        C[(m << 9) + n] = acc[am][bn][r];
      }
}

// ---------------- causal flash attention ----------------
// grid (32 qblocks, 32 bh), 4 waves/block, wave = 16 Q rows. KVBLK=32.
__global__ __launch_bounds__(256) void k_attn(const bf16* __restrict__ Qb,
                                              const bf16* __restrict__ Kb,
                                              const bf16* __restrict__ VTb,
                                              bf16* __restrict__ Oc) {
  __shared__ bf16 plds[4][16][40];   // padded row stride: 80B -> aligned b128, even banks
  const int tid = threadIdx.x, lane = tid & 63, w = tid >> 6;
  const int lr = lane & 15, lg = lane >> 4;
  const int bh = blockIdx.y, b = bh >> 3, h = bh & 7;
  const int s0 = blockIdx.x * 64 + w * 16;
  const bf16* Qh = Qb  + ((size_t)bh << 17);
  const bf16* Kh = Kb  + ((size_t)bh << 17);
  const bf16* Vh = VTb + ((size_t)bh << 17);

  bf16x8 qa0 = *(const bf16x8*)(Qh + ((s0 + lr) << 6) + 8 * lg);
  bf16x8 qa1 = *(const bf16x8*)(Qh + ((s0 + lr) << 6) + 32 + 8 * lg);

  f32x4 acc[4];
  #pragma unroll
  for (int bn = 0; bn < 4; ++bn) { f32x4 z = {0.f,0.f,0.f,0.f}; acc[bn] = z; }
  float m_run[4], l_run[4];
  #pragma unroll
  for (int r = 0; r < 4; ++r) { m_run[r] = -1e30f; l_run[r] = 0.f; }

  const int ntiles = ((s0 + 15) >> 5) + 1;
  for (int it = 0; it < ntiles; ++it) {
    const int tb = it << 5;
    // QK^T: 16 rows x 32 cols
    f32x4 sc[2];
    #pragma unroll
    for (int j = 0; j < 2; ++j) {
      const bf16* Krow = Kh + ((tb + j * 16 + lr) << 6) + 8 * lg;
      bf16x8 kb0 = *(const bf16x8*)(Krow);
      bf16x8 kb1 = *(const bf16x8*)(Krow + 32);
      f32x4 z = {0.f,0.f,0.f,0.f};
      z = __builtin_amdgcn_mfma_f32_16x16x32_bf16(qa0, kb0, z, 0, 0, 0);
      z = __builtin_amdgcn_mfma_f32_16x16x32_bf16(qa1, kb1, z, 0, 0, 0);
      sc[j] = z;
    }
    // online softmax (per row r: rows s0+4*lg+r; cols tb+j*16+lr)
    float p0a[4], p1a[4];
    #pragma unroll
    for (int r = 0; r < 4; ++r) {
      const int sg = s0 + 4 * lg + r;
      float x0 = sc[0][r] * 0.125f; if (tb + lr > sg)      x0 = -1e30f;
      float x1 = sc[1][r] * 0.125f; if (tb + 16 + lr > sg) x1 = -1e30f;
      float tmax = fmaxf(x0, x1);
      tmax = fmaxf(tmax, __shfl_xor(tmax, 1));
      tmax = fmaxf(tmax, __shfl_xor(tmax, 2));
      tmax = fmaxf(tmax, __shfl_xor(tmax, 4));
      tmax = fmaxf(tmax, __shfl_xor(tmax, 8));
      float mn  = fmaxf(m_run[r], tmax);
      float fac = __expf(m_run[r] - mn);
      float e0 = __expf(x0 - mn), e1 = __expf(x1 - mn);
      float rs = e0 + e1;
      rs += __shfl_xor(rs, 1);
      rs += __shfl_xor(rs, 2);
      rs += __shfl_xor(rs, 4);
      rs += __shfl_xor(rs, 8);
      l_run[r] = l_run[r] * fac + rs;
      m_run[r] = mn;
      p0a[r] = e0; p1a[r] = e1;
      acc[0][r] *= fac; acc[1][r] *= fac; acc[2][r] *= fac; acc[3][r] *= fac;
    }
    // transpose P through per-wave LDS into A-fragment layout
    bf16* P = &plds[w][0][0];
    #pragma unroll
    for (int r = 0; r < 4; ++r) {
      P[(4 * lg + r) * 40 + lr]      = (bf16)p0a[r];
      P[(4 * lg + r) * 40 + 16 + lr] = (bf16)p1a[r];
    }
    asm volatile("s_waitcnt lgkmcnt(0)" ::: "memory");
    bf16x8 pa = *(const bf16x8*)(P + lr * 40 + 8 * lg);
    // PV: O += P @ V   (V^T [dk][s] gives contiguous-8 along t)
    #pragma unroll
    for (int bn = 0; bn < 4; ++bn) {
      bf16x8 vb = *(const bf16x8*)(Vh + (((bn << 4) + lr) << 11) + tb + 8 * lg);
      acc[bn] = __builtin_amdgcn_mfma_f32_16x16x32_bf16(pa, vb, acc[bn], 0, 0, 0);
    }
  }
  // epilogue: normalize and write concat layout [b][s][dk*8+h]
  #pragma unroll
  for (int bn = 0; bn < 4; ++bn) {
    #pragma unroll
    for (int r = 0; r < 4; ++r) {
      int sg = s0 + 4 * lg + r;
      int dk = (bn << 4) + lr;
      float v = acc[bn][r] / l_run[r];
      Oc[((((b << 11) + sg) << 6) + dk) * 8 + h] = (bf16)v;
    }
  }
}

// ---------------- launch ----------------

extern "C" void kernel_launch(void* const* d_in, const int* in_sizes, int n_in,
                              void* d_out, int out_size, void* d_ws, size_t ws_size,
                              hipStream_t stream) {
  (void)in_sizes; (void)n_in; (void)out_size; (void)ws_size;
  const float* X  = (const float*)d_in[0];
  const float* Wq = (const float*)d_in[1];
  const float* Wk = (const float*)d_in[2];
  const float* Wv = (const float*)d_in[3];
  const float* Wo = (const float*)d_in[4];
  float* out = (float*)d_out;
  char* ws = (char*)d_ws;
  bf16* Xb   = (bf16*)(ws);
  bf16* Wqkv = (bf16*)(ws + 8388608);
  bf16* WoT  = (bf16*)(ws + 9961472);
  bf16* Qb   = (bf16*)(ws + 10485760);
  bf16* Kb   = (bf16*)(ws + 18874368);
  bf16* VTb  = (bf16*)(ws + 27262976);
  bf16* Oc   = (bf16*)(ws + 35651584);

  k_cvt_x<<<4096, 256, 0, stream>>>((const float4*)X, (bf16x4*)Xb);
  k_build_wqkv<<<3072, 256, 0, stream>>>(Wq, Wk, Wv, Wqkv);
  k_build_wo<<<1024, 256, 0, stream>>>(Wo, WoT);
  k_gemm_qkv<<<dim3(12, 64), 256, 0, stream>>>(Xb, Wqkv, Qb, Kb, VTb);
  k_attn<<<dim3(32, 32), 256, 0, stream>>>(Qb, Kb, VTb, Oc);
  k_gemm_out<<<dim3(4, 64), 256, 0, stream>>>(Oc, WoT, out);
}

// Round 2
// 146.116 us; speedup vs baseline: 1.9760x; 1.9760x over previous
//
#include <hip/hip_runtime.h>
#include <hip/hip_bf16.h>

// Problem constants: B=4, S=2048, D=512, H=8, DK=64
// ws layout (bytes):
//   Xb    @ 0        : 8192*512 bf16        = 8388608
//   Wqkv  @ 8388608  : 1536*512 bf16        = 1572864   (BT: row n = which*512+h*64+dk, col k=d)
//   WoT   @ 9961472  : 512*512 bf16         = 524288    (row d, col c=dk*8+h)
//   Qb    @ 10485760 : 32*2048*64 bf16      = 8388608   ([bh][s][dk])
//   Kb    @ 18874368 : 8388608                          ([bh][s][dk])
//   VTb   @ 27262976 : 8388608                          ([bh][dk][s])
//   Oc    @ 35651584 : 8388608                          ([b][s][dk*8+h] concat layout)
// total 44040192 bytes

typedef __bf16 bf16;
typedef __bf16 bf16x8 __attribute__((ext_vector_type(8)));
typedef __bf16 bf16x4 __attribute__((ext_vector_type(4)));
typedef float  f32x4  __attribute__((ext_vector_type(4)));
typedef float  f32x16 __attribute__((ext_vector_type(16)));
typedef unsigned int u32;
typedef u32 u32x4 __attribute__((ext_vector_type(4)));

#define AS1 __attribute__((address_space(1)))
#define AS3 __attribute__((address_space(3)))

__device__ __forceinline__ void async_lds16(const void* gsrc, void* ldst) {
  __builtin_amdgcn_global_load_lds((AS1 const void*)gsrc, (AS3 void*)ldst, 16, 0, 0);
}

// ---------------- converters ----------------

__global__ __launch_bounds__(256) void k_cvt_x(const float4* __restrict__ X,
                                               bf16x4* __restrict__ Xb) {
  int i = blockIdx.x * 256 + threadIdx.x;
  float4 v = X[i];
  bf16x4 o = { (bf16)v.x, (bf16)v.y, (bf16)v.z, (bf16)v.w };
  Xb[i] = o;
}

__global__ __launch_bounds__(256) void k_build_wqkv(const float* __restrict__ Wq,
                                                    const float* __restrict__ Wk,
                                                    const float* __restrict__ Wv,
                                                    bf16* __restrict__ BT) {
  int idx = blockIdx.x * 256 + threadIdx.x;     // < 1536*512
  int n = idx >> 9, d = idx & 511;
  int which = n >> 9, h = (n >> 6) & 7, dk = n & 63;
  const float* W = (which == 0) ? Wq : ((which == 1) ? Wk : Wv);
  BT[idx] = (bf16)W[((h << 9) + d) * 64 + dk];
}

__global__ __launch_bounds__(256) void k_build_wo(const float* __restrict__ Wo,
                                                  bf16* __restrict__ WoT) {
  int idx = blockIdx.x * 256 + threadIdx.x;     // < 512*512
  int d = idx >> 9, c = idx & 511;
  WoT[idx] = (bf16)Wo[(c << 9) + d];
}

// ---------------- GEMM mainloop (128x128 tile, BK=32, 4 waves) ----------------

__device__ __forceinline__ void gemm_tile(const bf16* __restrict__ A,
                                          const bf16* __restrict__ BT,
                                          int K, int m0, int n0,
                                          char* sm, f32x4 acc[4][4]) {
  const int tid = threadIdx.x;
  const int lane = tid & 63, w = tid >> 6;
  const int wm = w >> 1, wn = w & 1;
  const int lr = lane & 15, lg = lane >> 4;
  for (int k0 = 0; k0 < K; k0 += 32) {
    __syncthreads();
    #pragma unroll
    for (int i = 0; i < 2; ++i) {
      int off16 = i * 256 + tid;
      int row   = off16 >> 2;
      int colb  = (off16 & 3) << 4;
      const char* srcA = (const char*)(A  + (m0 + row) * K + k0) + colb;
      const char* srcB = (const char*)(BT + (n0 + row) * K + k0) + colb;
      async_lds16(srcA, sm +        (i * 256 + w * 64) * 16);
      async_lds16(srcB, sm + 8192 + (i * 256 + w * 64) * 16);
    }
    __syncthreads();
    bf16x8 af[4], bfr[4];
    #pragma unroll
    for (int t = 0; t < 4; ++t) {
      af[t]  = *(const bf16x8*)(sm +        ((wm * 64 + t * 16 + lr) * 32 + 8 * lg) * 2);
      bfr[t] = *(const bf16x8*)(sm + 8192 + ((wn * 64 + t * 16 + lr) * 32 + 8 * lg) * 2);
    }
    #pragma unroll
    for (int am = 0; am < 4; ++am)
      #pragma unroll
      for (int bn = 0; bn < 4; ++bn)
        acc[am][bn] = __builtin_amdgcn_mfma_f32_16x16x32_bf16(af[am], bfr[bn], acc[am][bn], 0, 0, 0);
  }
}

__global__ __launch_bounds__(256) void k_gemm_qkv(const bf16* __restrict__ A,
                                                  const bf16* __restrict__ BT,
                                                  bf16* __restrict__ Qb,
                                                  bf16* __restrict__ Kb,
                                                  bf16* __restrict__ VTb) {
  __shared__ char sm[16384];
  const int m0 = blockIdx.y * 128, n0 = blockIdx.x * 128;
  f32x4 acc[4][4];
  #pragma unroll
  for (int a = 0; a < 4; ++a)
    #pragma unroll
    for (int b = 0; b < 4; ++b) { f32x4 z = {0.f,0.f,0.f,0.f}; acc[a][b] = z; }
  gemm_tile(A, BT, 512, m0, n0, sm, acc);
  const int lane = threadIdx.x & 63, w = threadIdx.x >> 6;
  const int wm = w >> 1, wn = w & 1, lr = lane & 15, lg = lane >> 4;
  #pragma unroll
  for (int am = 0; am < 4; ++am)
    #pragma unroll
    for (int bn = 0; bn < 4; ++bn)
      #pragma unroll
      for (int r = 0; r < 4; ++r) {
        int m = m0 + wm * 64 + am * 16 + 4 * lg + r;
        int n = n0 + wn * 64 + bn * 16 + lr;
        int b = m >> 11, s = m & 2047;
        int which = n >> 9, h = (n >> 6) & 7, dk = n & 63;
        int bh = (b << 3) + h;
        bf16 v = (bf16)acc[am][bn][r];
        if (which == 0)      Qb[((bh << 11) + s) * 64 + dk] = v;
        else if (which == 1) Kb[((bh << 11) + s) * 64 + dk] = v;
        else                 VTb[((bh << 6) + dk) * 2048 + s] = v;
      }
}

__global__ __launch_bounds__(256) void k_gemm_out(const bf16* __restrict__ A,
                                                  const bf16* __restrict__ BT,
                                                  float* __restrict__ C) {
  __shared__ char sm[16384];
  const int m0 = blockIdx.y * 128, n0 = blockIdx.x * 128;
  f32x4 acc[4][4];
  #pragma unroll
  for (int a = 0; a < 4; ++a)
    #pragma unroll
    for (int b = 0; b < 4; ++b) { f32x4 z = {0.f,0.f,0.f,0.f}; acc[a][b] = z; }
  gemm_tile(A, BT, 512, m0, n0, sm, acc);
  const int lane = threadIdx.x & 63, w = threadIdx.x >> 6;
  const int wm = w >> 1, wn = w & 1, lr = lane & 15, lg = lane >> 4;
  #pragma unroll
  for (int am = 0; am < 4; ++am)
    #pragma unroll
    for (int bn = 0; bn < 4; ++bn)
      #pragma unroll
      for (int r = 0; r < 4; ++r) {
        int m = m0 + wm * 64 + am * 16 + 4 * lg + r;
        int n = n0 + wn * 64 + bn * 16 + lr;
        C[(m << 9) + n] = acc[am][bn][r];
      }
}

// ---------------- causal flash attention, swapped-operand, zero-LDS ----------------
// 1 wave per block, 32 Q-rows per wave, KV tile = 32.
// QK^T: mfma(A=K, B=Q) -> S^T: lane holds 16 scores of ONE q-row (col = lane&31).
// PV:   mfma(A=V^T, B=P) -> O^T: lane holds O[q=lane&31][16 dv regs]; softmax state lane-local.
// C/D map (32x32): col = lane&31, row = (reg&3) + 8*(reg>>2) + 4*(lane>>5).
// A/B map (32x32x16): row/col = lane&31, k = 8*(lane>>5) + j.

__global__ __launch_bounds__(64) void k_attn2(const bf16* __restrict__ Qb,
                                              const bf16* __restrict__ Kb,
                                              const bf16* __restrict__ VTb,
                                              bf16* __restrict__ Oc) {
  const int lane = threadIdx.x;
  const int l31 = lane & 31, hi = lane >> 5;
  const int bh = blockIdx.x, b = bh >> 3, h = bh & 7;
  const int qt = 63 - (int)blockIdx.y;           // longest-first dispatch
  const int q0 = qt << 5;
  const bf16* Qh = Qb  + ((size_t)bh << 17);
  const bf16* Kh = Kb  + ((size_t)bh << 17);
  const bf16* Vh = VTb + ((size_t)bh << 17);
  const float kSc = 0.125f * 1.44269504089f;     // 1/sqrt(64) * log2(e)

  // Q B-fragments (stay in registers)
  bf16x8 qf[4];
  #pragma unroll
  for (int kd = 0; kd < 4; ++kd)
    qf[kd] = *(const bf16x8*)(Qh + ((q0 + l31) << 6) + kd * 16 + 8 * hi);

  f32x16 o0, o1;
  #pragma unroll
  for (int r = 0; r < 16; ++r) { o0[r] = 0.f; o1[r] = 0.f; }
  float m_run = -3e38f, lsum = 0.f;

  const int ntiles = qt + 1;
  bf16x8 kf[4], kn[4];
  #pragma unroll
  for (int kd = 0; kd < 4; ++kd)
    kf[kd] = *(const bf16x8*)(Kh + (l31 << 6) + kd * 16 + 8 * hi);

  for (int t = 0; t < ntiles; ++t) {
    const int tb = t << 5;
    // QK^T (S^T tile)
    f32x16 s;
    #pragma unroll
    for (int r = 0; r < 16; ++r) s[r] = 0.f;
    #pragma unroll
    for (int kd = 0; kd < 4; ++kd)
      s = __builtin_amdgcn_mfma_f32_32x32x16_bf16(kf[kd], qf[kd], s, 0, 0, 0);

    // prefetch next K tile (covered by softmax+PV latency)
    if (t + 1 < ntiles) {
      #pragma unroll
      for (int kd = 0; kd < 4; ++kd)
        kn[kd] = *(const bf16x8*)(Kh + ((tb + 32 + l31) << 6) + kd * 16 + 8 * hi);
    }
    // V^T A-fragments for this tile
    bf16x8 vf[2][2];
    #pragma unroll
    for (int dvt = 0; dvt < 2; ++dvt)
      #pragma unroll
      for (int ks = 0; ks < 2; ++ks)
        vf[dvt][ks] = *(const bf16x8*)(Vh + (((dvt << 5) + l31) << 11) + tb + ks * 16 + 8 * hi);

    // causal mask (only the diagonal tile needs it)
    if (t == ntiles - 1) {
      #pragma unroll
      for (int r = 0; r < 16; ++r) {
        int rk = (r & 3) + 8 * (r >> 2) + 4 * hi;
        s[r] = (rk > l31) ? -1e30f : s[r];
      }
    }
    // row max: in-lane tree + one cross-half exchange
    float tv[16];
    #pragma unroll
    for (int r = 0; r < 16; ++r) tv[r] = s[r];
    #pragma unroll
    for (int st = 8; st > 0; st >>= 1)
      #pragma unroll
      for (int i = 0; i < 16; ++i) if (i < st) tv[i] = fmaxf(tv[i], tv[i + st]);
    float tmax = fmaxf(tv[0], __shfl_xor(tv[0], 32));
    float tms = tmax * kSc;
    // defer-max rescale (T13, THR=8 in exp2 domain)
    if (!__all(tms <= m_run + 8.f)) {
      float mn = fmaxf(m_run, tms);
      float fac = exp2f(m_run - mn);
      #pragma unroll
      for (int r = 0; r < 16; ++r) { o0[r] *= fac; o1[r] *= fac; }
      lsum *= fac;
      m_run = mn;
    }
    // P = exp2(s*kSc - m)
    float p[16];
    #pragma unroll
    for (int r = 0; r < 16; ++r) p[r] = exp2f(fmaf(s[r], kSc, -m_run));
    // row sum
    float sv[16];
    #pragma unroll
    for (int r = 0; r < 16; ++r) sv[r] = p[r];
    #pragma unroll
    for (int st = 8; st > 0; st >>= 1)
      #pragma unroll
      for (int i = 0; i < 16; ++i) if (i < st) sv[i] += sv[i + st];
    lsum += sv[0] + __shfl_xor(sv[0], 32);

    // pack P to bf16 pairs; cross-half exchange builds PV B-fragments
    u32 pk_[8], sw_[8];
    #pragma unroll
    for (int i = 0; i < 8; ++i) {
      unsigned short x = __builtin_bit_cast(unsigned short, (bf16)p[2 * i]);
      unsigned short y = __builtin_bit_cast(unsigned short, (bf16)p[2 * i + 1]);
      pk_[i] = (u32)x | ((u32)y << 16);
    }
    #pragma unroll
    for (int i = 0; i < 8; ++i) sw_[i] = __shfl_xor(pk_[i], 32);
    bf16x8 pb[2];
    #pragma unroll
    for (int ks = 0; ks < 2; ++ks) {
      u32x4 wv;
      wv.x = hi ? sw_[4 * ks + 2] : pk_[4 * ks + 0];
      wv.y = hi ? sw_[4 * ks + 3] : pk_[4 * ks + 1];
      wv.z = hi ? pk_[4 * ks + 2] : sw_[4 * ks + 0];
      wv.w = hi ? pk_[4 * ks + 3] : sw_[4 * ks + 1];
      pb[ks] = __builtin_bit_cast(bf16x8, wv);
    }
    // PV (O^T accumulate)
    o0 = __builtin_amdgcn_mfma_f32_32x32x16_bf16(vf[0][0], pb[0], o0, 0, 0, 0);
    o0 = __builtin_amdgcn_mfma_f32_32x32x16_bf16(vf[0][1], pb[1], o0, 0, 0, 0);
    o1 = __builtin_amdgcn_mfma_f32_32x32x16_bf16(vf[1][0], pb[0], o1, 0, 0, 0);
    o1 = __builtin_amdgcn_mfma_f32_32x32x16_bf16(vf[1][1], pb[1], o1, 0, 0, 0);
    #pragma unroll
    for (int kd = 0; kd < 4; ++kd) kf[kd] = kn[kd];
  }
  // epilogue: normalize (lane-local l) and write concat layout [b][s][dk*8+h]
  float rn = 1.f / lsum;
  const int sg = q0 + l31;
  const size_t base = ((size_t)((b << 11) + sg) << 6);
  #pragma unroll
  for (int r = 0; r < 16; ++r) {
    int dv0 = (r & 3) + 8 * (r >> 2) + 4 * hi;
    Oc[(base + dv0) * 8 + h]      = (bf16)(o0[r] * rn);
    Oc[(base + dv0 + 32) * 8 + h] = (bf16)(o1[r] * rn);
  }
}

// ---------------- launch ----------------

extern "C" void kernel_launch(void* const* d_in, const int* in_sizes, int n_in,
                              void* d_out, int out_size, void* d_ws, size_t ws_size,
                              hipStream_t stream) {
  (void)in_sizes; (void)n_in; (void)out_size; (void)ws_size;
  const float* X  = (const float*)d_in[0];
  const float* Wq = (const float*)d_in[1];
  const float* Wk = (const float*)d_in[2];
  const float* Wv = (const float*)d_in[3];
  const float* Wo = (const float*)d_in[4];
  float* out = (float*)d_out;
  char* ws = (char*)d_ws;
  bf16* Xb   = (bf16*)(ws);
  bf16* Wqkv = (bf16*)(ws + 8388608);
  bf16* WoT  = (bf16*)(ws + 9961472);
  bf16* Qb   = (bf16*)(ws + 10485760);
  bf16* Kb   = (bf16*)(ws + 18874368);
  bf16* VTb  = (bf16*)(ws + 27262976);
  bf16* Oc   = (bf16*)(ws + 35651584);

  k_cvt_x<<<4096, 256, 0, stream>>>((const float4*)X, (bf16x4*)Xb);
  k_build_wqkv<<<3072, 256, 0, stream>>>(Wq, Wk, Wv, Wqkv);
  k_build_wo<<<1024, 256, 0, stream>>>(Wo, WoT);
  k_gemm_qkv<<<dim3(12, 64), 256, 0, stream>>>(Xb, Wqkv, Qb, Kb, VTb);
  k_attn2<<<dim3(32, 64), 64, 0, stream>>>(Qb, Kb, VTb, Oc);
  k_gemm_out<<<dim3(4, 64), 256, 0, stream>>>(Oc, WoT, out);
}

// Round 3
// 136.653 us; speedup vs baseline: 2.1128x; 1.0693x over previous
//
#include <hip/hip_runtime.h>
#include <hip/hip_bf16.h>

// Problem constants: B=4, S=2048, D=512, H=8, DK=64
// ws layout (bytes):
//   Xb    @ 0        : 8192*512 bf16        = 8388608
//   Wqkv  @ 8388608  : 1536*512 bf16        = 1572864   (BT: row n = which*512+h*64+dk, col k=d)
//   WoT   @ 9961472  : 512*512 bf16         = 524288    (row n=d, col k=h*64+dk  [permuted concat])
//   Qb    @ 10485760 : 32*2048*64 bf16      = 8388608   ([bh][s][dk])
//   Kb    @ 18874368 : 8388608                          ([bh][s][dk])
//   VTb   @ 27262976 : 8388608                          ([bh][dk][s])
//   Oc    @ 35651584 : 8388608                          ([b][s][h*64+dk])
// total 44040192 bytes

typedef __bf16 bf16;
typedef __bf16 bf16x8 __attribute__((ext_vector_type(8)));
typedef __bf16 bf16x4 __attribute__((ext_vector_type(4)));
typedef float  f32x4  __attribute__((ext_vector_type(4)));
typedef float  f32x16 __attribute__((ext_vector_type(16)));
typedef unsigned int u32;
typedef u32 u32x4 __attribute__((ext_vector_type(4)));

#define AS1 __attribute__((address_space(1)))
#define AS3 __attribute__((address_space(3)))

__device__ __forceinline__ void async_lds16(const void* gsrc, void* ldst) {
  __builtin_amdgcn_global_load_lds((AS1 const void*)gsrc, (AS3 void*)ldst, 16, 0, 0);
}

// ---------------- converters ----------------

__global__ __launch_bounds__(256) void k_cvt_x(const float4* __restrict__ X,
                                               bf16x4* __restrict__ Xb) {
  int i = blockIdx.x * 256 + threadIdx.x;
  float4 v = X[i];
  bf16x4 o = { (bf16)v.x, (bf16)v.y, (bf16)v.z, (bf16)v.w };
  Xb[i] = o;
}

__global__ __launch_bounds__(256) void k_build_wqkv(const float* __restrict__ Wq,
                                                    const float* __restrict__ Wk,
                                                    const float* __restrict__ Wv,
                                                    bf16* __restrict__ BT) {
  int idx = blockIdx.x * 256 + threadIdx.x;     // < 1536*512
  int n = idx >> 9, d = idx & 511;
  int which = n >> 9, h = (n >> 6) & 7, dk = n & 63;
  const float* W = (which == 0) ? Wq : ((which == 1) ? Wk : Wv);
  BT[idx] = (bf16)W[((h << 9) + d) * 64 + dk];
}

// WoT[n=d][k=c], c = h*64+dk (attention O layout); Wo row = dk*8+h
__global__ __launch_bounds__(256) void k_build_wo(const float* __restrict__ Wo,
                                                  bf16* __restrict__ WoT) {
  int idx = blockIdx.x * 256 + threadIdx.x;     // < 512*512
  int d = idx >> 9, c = idx & 511;
  int h = c >> 6, dk = c & 63;
  WoT[idx] = (bf16)Wo[(((dk << 3) + h) << 9) + d];
}

// ---------------- GEMM mainloop (128x128 tile, BK=32, 4 waves) ----------------

__device__ __forceinline__ void gemm_tile(const bf16* __restrict__ A,
                                          const bf16* __restrict__ BT,
                                          int K, int m0, int n0,
                                          char* sm, f32x4 acc[4][4]) {
  const int tid = threadIdx.x;
  const int lane = tid & 63, w = tid >> 6;
  const int wm = w >> 1, wn = w & 1;
  const int lr = lane & 15, lg = lane >> 4;
  for (int k0 = 0; k0 < K; k0 += 32) {
    __syncthreads();
    #pragma unroll
    for (int i = 0; i < 2; ++i) {
      int off16 = i * 256 + tid;
      int row   = off16 >> 2;
      int colb  = (off16 & 3) << 4;
      const char* srcA = (const char*)(A  + (m0 + row) * K + k0) + colb;
      const char* srcB = (const char*)(BT + (n0 + row) * K + k0) + colb;
      async_lds16(srcA, sm +        (i * 256 + w * 64) * 16);
      async_lds16(srcB, sm + 8192 + (i * 256 + w * 64) * 16);
    }
    __syncthreads();
    bf16x8 af[4], bfr[4];
    #pragma unroll
    for (int t = 0; t < 4; ++t) {
      af[t]  = *(const bf16x8*)(sm +        ((wm * 64 + t * 16 + lr) * 32 + 8 * lg) * 2);
      bfr[t] = *(const bf16x8*)(sm + 8192 + ((wn * 64 + t * 16 + lr) * 32 + 8 * lg) * 2);
    }
    #pragma unroll
    for (int am = 0; am < 4; ++am)
      #pragma unroll
      for (int bn = 0; bn < 4; ++bn)
        acc[am][bn] = __builtin_amdgcn_mfma_f32_16x16x32_bf16(af[am], bfr[bn], acc[am][bn], 0, 0, 0);
  }
}

__global__ __launch_bounds__(256) void k_gemm_qkv(const bf16* __restrict__ A,
                                                  const bf16* __restrict__ BT,
                                                  bf16* __restrict__ Qb,
                                                  bf16* __restrict__ Kb,
                                                  bf16* __restrict__ VTb) {
  __shared__ char sm[16384];
  const int m0 = blockIdx.y * 128, n0 = blockIdx.x * 128;
  f32x4 acc[4][4];
  #pragma unroll
  for (int a = 0; a < 4; ++a)
    #pragma unroll
    for (int b = 0; b < 4; ++b) { f32x4 z = {0.f,0.f,0.f,0.f}; acc[a][b] = z; }
  gemm_tile(A, BT, 512, m0, n0, sm, acc);
  const int lane = threadIdx.x & 63, w = threadIdx.x >> 6;
  const int wm = w >> 1, wn = w & 1, lr = lane & 15, lg = lane >> 4;
  #pragma unroll
  for (int am = 0; am < 4; ++am)
    #pragma unroll
    for (int bn = 0; bn < 4; ++bn)
      #pragma unroll
      for (int r = 0; r < 4; ++r) {
        int m = m0 + wm * 64 + am * 16 + 4 * lg + r;
        int n = n0 + wn * 64 + bn * 16 + lr;
        int b = m >> 11, s = m & 2047;
        int which = n >> 9, h = (n >> 6) & 7, dk = n & 63;
        int bh = (b << 3) + h;
        bf16 v = (bf16)acc[am][bn][r];
        if (which == 0)      Qb[((bh << 11) + s) * 64 + dk] = v;
        else if (which == 1) Kb[((bh << 11) + s) * 64 + dk] = v;
        else                 VTb[((bh << 6) + dk) * 2048 + s] = v;
      }
}

__global__ __launch_bounds__(256) void k_gemm_out(const bf16* __restrict__ A,
                                                  const bf16* __restrict__ BT,
                                                  float* __restrict__ C) {
  __shared__ char sm[16384];
  const int m0 = blockIdx.y * 128, n0 = blockIdx.x * 128;
  f32x4 acc[4][4];
  #pragma unroll
  for (int a = 0; a < 4; ++a)
    #pragma unroll
    for (int b = 0; b < 4; ++b) { f32x4 z = {0.f,0.f,0.f,0.f}; acc[a][b] = z; }
  gemm_tile(A, BT, 512, m0, n0, sm, acc);
  const int lane = threadIdx.x & 63, w = threadIdx.x >> 6;
  const int wm = w >> 1, wn = w & 1, lr = lane & 15, lg = lane >> 4;
  #pragma unroll
  for (int am = 0; am < 4; ++am)
    #pragma unroll
    for (int bn = 0; bn < 4; ++bn)
      #pragma unroll
      for (int r = 0; r < 4; ++r) {
        int m = m0 + wm * 64 + am * 16 + 4 * lg + r;
        int n = n0 + wn * 64 + bn * 16 + lr;
        C[(m << 9) + n] = acc[am][bn][r];
      }
}

// ---------------- causal flash attention, swapped-operand, zero-LDS ----------------
// 1 wave per block, 32 Q-rows, KV tile = 64 (two 32-col halves).
// QK^T: mfma(A=K, B=Q) -> S^T: lane holds scores of ONE q-row (q = lane&31).
// PV:   mfma(A=V^T, B=P) -> O^T: softmax state fully lane-local.
// C/D map (32x32): col = lane&31, row = (reg&3) + 8*(reg>>2) + 4*(lane>>5).

__global__ __launch_bounds__(64) void k_attn2(const bf16* __restrict__ Qb,
                                              const bf16* __restrict__ Kb,
                                              const bf16* __restrict__ VTb,
                                              bf16* __restrict__ Oc) {
  const int lane = threadIdx.x;
  const int l31 = lane & 31, hi = lane >> 5;
  const int bh = blockIdx.x, b = bh >> 3, h = bh & 7;
  const int qt = 63 - (int)blockIdx.y;           // longest-first dispatch
  const int q0 = qt << 5;
  const bf16* Qh = Qb  + ((size_t)bh << 17);
  const bf16* Kh = Kb  + ((size_t)bh << 17);
  const bf16* Vh = VTb + ((size_t)bh << 17);
  const float kSc = 0.125f * 1.44269504089f;     // 1/sqrt(64) * log2(e)

  bf16x8 qf[4];
  #pragma unroll
  for (int kd = 0; kd < 4; ++kd)
    qf[kd] = *(const bf16x8*)(Qh + ((q0 + l31) << 6) + kd * 16 + 8 * hi);

  f32x16 o0, o1;
  #pragma unroll
  for (int r = 0; r < 16; ++r) { o0[r] = 0.f; o1[r] = 0.f; }
  float m_run = -3e38f, lsum = 0.f;

  const int NT = (qt >> 1) + 1;                  // ceil((q0+32)/64)
  bf16x8 kf[8], kn[8];
  #pragma unroll
  for (int j = 0; j < 2; ++j)
    #pragma unroll
    for (int kd = 0; kd < 4; ++kd)
      kf[j * 4 + kd] = *(const bf16x8*)(Kh + (((j << 5) + l31) << 6) + kd * 16 + 8 * hi);

  for (int t = 0; t < NT; ++t) {
    const int tb = t << 6;
    // QK^T: two 32-col halves
    f32x16 sA, sB;
    #pragma unroll
    for (int r = 0; r < 16; ++r) { sA[r] = 0.f; sB[r] = 0.f; }
    __builtin_amdgcn_s_setprio(1);
    #pragma unroll
    for (int kd = 0; kd < 4; ++kd)
      sA = __builtin_amdgcn_mfma_f32_32x32x16_bf16(kf[kd], qf[kd], sA, 0, 0, 0);
    #pragma unroll
    for (int kd = 0; kd < 4; ++kd)
      sB = __builtin_amdgcn_mfma_f32_32x32x16_bf16(kf[4 + kd], qf[kd], sB, 0, 0, 0);
    __builtin_amdgcn_s_setprio(0);

    // V fragments for THIS tile: issued now, consumed after softmax
    bf16x8 vf[2][2][2];  // [half j][dvt][ks]
    #pragma unroll
    for (int j = 0; j < 2; ++j)
      #pragma unroll
      for (int dvt = 0; dvt < 2; ++dvt)
        #pragma unroll
        for (int ks = 0; ks < 2; ++ks)
          vf[j][dvt][ks] = *(const bf16x8*)(Vh + (((dvt << 5) + l31) << 11) + tb + (j << 5) + (ks << 4) + 8 * hi);

    // K prefetch for next tile
    if (t + 1 < NT) {
      #pragma unroll
      for (int j = 0; j < 2; ++j)
        #pragma unroll
        for (int kd = 0; kd < 4; ++kd)
          kn[j * 4 + kd] = *(const bf16x8*)(Kh + ((tb + 64 + (j << 5) + l31) << 6) + kd * 16 + 8 * hi);
    }

    // causal mask (diagonal tile only)
    if (t == NT - 1) {
      const int sg = q0 + l31;
      #pragma unroll
      for (int r = 0; r < 16; ++r) {
        int rk = tb + (r & 3) + 8 * (r >> 2) + 4 * hi;
        sA[r] = (rk > sg)      ? -1e30f : sA[r];
        sB[r] = (rk + 32 > sg) ? -1e30f : sB[r];
      }
    }
    // row max: in-lane tree over 32 + one cross-half exchange
    float tv[16];
    #pragma unroll
    for (int r = 0; r < 16; ++r) tv[r] = fmaxf(sA[r], sB[r]);
    #pragma unroll
    for (int st = 8; st > 0; st >>= 1)
      #pragma unroll
      for (int i = 0; i < 16; ++i) if (i < st) tv[i] = fmaxf(tv[i], tv[i + st]);
    float tms = fmaxf(tv[0], __shfl_xor(tv[0], 32)) * kSc;
    // defer-max rescale (T13, THR=8 in exp2 domain)
    if (!__all(tms <= m_run + 8.f)) {
      float mn = fmaxf(m_run, tms);
      float fac = exp2f(m_run - mn);
      #pragma unroll
      for (int r = 0; r < 16; ++r) { o0[r] *= fac; o1[r] *= fac; }
      lsum *= fac;
      m_run = mn;
    }
    // P = exp2(s*kSc - m)
    float pA[16], pB[16];
    #pragma unroll
    for (int r = 0; r < 16; ++r) pA[r] = exp2f(fmaf(sA[r], kSc, -m_run));
    #pragma unroll
    for (int r = 0; r < 16; ++r) pB[r] = exp2f(fmaf(sB[r], kSc, -m_run));
    // row sum
    float sv[16];
    #pragma unroll
    for (int r = 0; r < 16; ++r) sv[r] = pA[r] + pB[r];
    #pragma unroll
    for (int st = 8; st > 0; st >>= 1)
      #pragma unroll
      for (int i = 0; i < 16; ++i) if (i < st) sv[i] += sv[i + st];
    lsum += sv[0] + __shfl_xor(sv[0], 32);

    // pack P -> bf16 pairs; permlane32_swap builds PV B-fragments in-register
    #pragma unroll
    for (int j = 0; j < 2; ++j) {
      const float* p = j ? pB : pA;
      u32 pk_[8];
      #pragma unroll
      for (int i = 0; i < 8; ++i) {
        unsigned short x = __builtin_bit_cast(unsigned short, (bf16)p[2 * i]);
        unsigned short y = __builtin_bit_cast(unsigned short, (bf16)p[2 * i + 1]);
        pk_[i] = (u32)x | ((u32)y << 16);
      }
      // {w0,w2} = swap(pk0,pk2); {w1,w3} = swap(pk1,pk3); same for ks=1
      asm volatile("v_permlane32_swap_b32 %0, %1" : "+v"(pk_[0]), "+v"(pk_[2]));
      asm volatile("v_permlane32_swap_b32 %0, %1" : "+v"(pk_[1]), "+v"(pk_[3]));
      asm volatile("v_permlane32_swap_b32 %0, %1" : "+v"(pk_[4]), "+v"(pk_[6]));
      asm volatile("v_permlane32_swap_b32 %0, %1" : "+v"(pk_[5]), "+v"(pk_[7]));
      u32x4 w0 = { pk_[0], pk_[1], pk_[2], pk_[3] };
      u32x4 w1 = { pk_[4], pk_[5], pk_[6], pk_[7] };
      bf16x8 pb0 = __builtin_bit_cast(bf16x8, w0);
      bf16x8 pb1 = __builtin_bit_cast(bf16x8, w1);
      __builtin_amdgcn_s_setprio(1);
      o0 = __builtin_amdgcn_mfma_f32_32x32x16_bf16(vf[j][0][0], pb0, o0, 0, 0, 0);
      o0 = __builtin_amdgcn_mfma_f32_32x32x16_bf16(vf[j][0][1], pb1, o0, 0, 0, 0);
      o1 = __builtin_amdgcn_mfma_f32_32x32x16_bf16(vf[j][1][0], pb0, o1, 0, 0, 0);
      o1 = __builtin_amdgcn_mfma_f32_32x32x16_bf16(vf[j][1][1], pb1, o1, 0, 0, 0);
      __builtin_amdgcn_s_setprio(0);
    }
    #pragma unroll
    for (int i = 0; i < 8; ++i) kf[i] = kn[i];
  }
  // epilogue: normalize (lane-local l), coalesced write to [b][s][h*64+dk]
  float rn = 1.f / lsum;
  const int sg = q0 + l31;
  bf16* Orow = Oc + (((size_t)((b << 11) + sg)) << 9) + (h << 6);
  #pragma unroll
  for (int g = 0; g < 4; ++g) {
    bf16x4 v0 = { (bf16)(o0[4*g]*rn), (bf16)(o0[4*g+1]*rn), (bf16)(o0[4*g+2]*rn), (bf16)(o0[4*g+3]*rn) };
    bf16x4 v1 = { (bf16)(o1[4*g]*rn), (bf16)(o1[4*g+1]*rn), (bf16)(o1[4*g+2]*rn), (bf16)(o1[4*g+3]*rn) };
    *(bf16x4*)(Orow + 4 * hi + 8 * g)      = v0;
    *(bf16x4*)(Orow + 32 + 4 * hi + 8 * g) = v1;
  }
}

// ---------------- launch ----------------

extern "C" void kernel_launch(void* const* d_in, const int* in_sizes, int n_in,
                              void* d_out, int out_size, void* d_ws, size_t ws_size,
                              hipStream_t stream) {
  (void)in_sizes; (void)n_in; (void)out_size; (void)ws_size;
  const float* X  = (const float*)d_in[0];
  const float* Wq = (const float*)d_in[1];
  const float* Wk = (const float*)d_in[2];
  const float* Wv = (const float*)d_in[3];
  const float* Wo = (const float*)d_in[4];
  float* out = (float*)d_out;
  char* ws = (char*)d_ws;
  bf16* Xb   = (bf16*)(ws);
  bf16* Wqkv = (bf16*)(ws + 8388608);
  bf16* WoT  = (bf16*)(ws + 9961472);
  bf16* Qb   = (bf16*)(ws + 10485760);
  bf16* Kb   = (bf16*)(ws + 18874368);
  bf16* VTb  = (bf16*)(ws + 27262976);
  bf16* Oc   = (bf16*)(ws + 35651584);

  k_cvt_x<<<4096, 256, 0, stream>>>((const float4*)X, (bf16x4*)Xb);
  k_build_wqkv<<<3072, 256, 0, stream>>>(Wq, Wk, Wv, Wqkv);
  k_build_wo<<<1024, 256, 0, stream>>>(Wo, WoT);
  k_gemm_qkv<<<dim3(12, 64), 256, 0, stream>>>(Xb, Wqkv, Qb, Kb, VTb);
  k_attn2<<<dim3(32, 64), 64, 0, stream>>>(Qb, Kb, VTb, Oc);
  k_gemm_out<<<dim3(4, 64), 256, 0, stream>>>(Oc, WoT, out);
}

// Round 4
// 132.589 us; speedup vs baseline: 2.1775x; 1.0306x over previous
//
#include <hip/hip_runtime.h>
#include <hip/hip_bf16.h>

// Problem constants: B=4, S=2048, D=512, H=8, DK=64
// ws layout (bytes):
//   Xb    @ 0        : 8192*512 bf16        = 8388608
//   Wqkv  @ 8388608  : 1536*512 bf16        = 1572864   (BT: row n = which*512+h*64+dk, col k=d)
//   WoT   @ 9961472  : 512*512 bf16         = 524288    (row n=d, col k=h*64+dk  [permuted concat])
//   Qb    @ 10485760 : 32*2048*64 bf16      = 8388608   ([bh][s][dk])
//   Kb    @ 18874368 : 8388608                          ([bh][s][dk])
//   VTb   @ 27262976 : 8388608                          ([bh][dk][s])
//   Oc    @ 35651584 : 8388608                          ([b][s][h*64+dk])
// total 44040192 bytes

typedef __bf16 bf16;
typedef __bf16 bf16x8 __attribute__((ext_vector_type(8)));
typedef __bf16 bf16x4 __attribute__((ext_vector_type(4)));
typedef float  f32x4  __attribute__((ext_vector_type(4)));
typedef float  f32x16 __attribute__((ext_vector_type(16)));
typedef unsigned int u32;
typedef u32 u32x4 __attribute__((ext_vector_type(4)));

#define AS1 __attribute__((address_space(1)))
#define AS3 __attribute__((address_space(3)))

__device__ __forceinline__ void async_lds16(const void* gsrc, void* ldst) {
  __builtin_amdgcn_global_load_lds((AS1 const void*)gsrc, (AS3 void*)ldst, 16, 0, 0);
}

// ---------------- converters ----------------

__global__ __launch_bounds__(256) void k_cvt_x(const float4* __restrict__ X,
                                               bf16x4* __restrict__ Xb) {
  int i = blockIdx.x * 256 + threadIdx.x;
  float4 v = X[i];
  bf16x4 o = { (bf16)v.x, (bf16)v.y, (bf16)v.z, (bf16)v.w };
  Xb[i] = o;
}

__global__ __launch_bounds__(256) void k_build_wqkv(const float* __restrict__ Wq,
                                                    const float* __restrict__ Wk,
                                                    const float* __restrict__ Wv,
                                                    bf16* __restrict__ BT) {
  int idx = blockIdx.x * 256 + threadIdx.x;     // < 1536*512
  int n = idx >> 9, d = idx & 511;
  int which = n >> 9, h = (n >> 6) & 7, dk = n & 63;
  const float* W = (which == 0) ? Wq : ((which == 1) ? Wk : Wv);
  BT[idx] = (bf16)W[((h << 9) + d) * 64 + dk];
}

// WoT[n=d][k=c], c = h*64+dk (attention O layout); Wo row = dk*8+h
__global__ __launch_bounds__(256) void k_build_wo(const float* __restrict__ Wo,
                                                  bf16* __restrict__ WoT) {
  int idx = blockIdx.x * 256 + threadIdx.x;     // < 512*512
  int d = idx >> 9, c = idx & 511;
  int h = c >> 6, dk = c & 63;
  WoT[idx] = (bf16)Wo[(((dk << 3) + h) << 9) + d];
}

// ---------------- GEMM mainloop (128x128 tile, BK=32, 4 waves) ----------------

__device__ __forceinline__ void gemm_tile(const bf16* __restrict__ A,
                                          const bf16* __restrict__ BT,
                                          int K, int m0, int n0,
                                          char* sm, f32x4 acc[4][4]) {
  const int tid = threadIdx.x;
  const int lane = tid & 63, w = tid >> 6;
  const int wm = w >> 1, wn = w & 1;
  const int lr = lane & 15, lg = lane >> 4;
  for (int k0 = 0; k0 < K; k0 += 32) {
    __syncthreads();
    #pragma unroll
    for (int i = 0; i < 2; ++i) {
      int off16 = i * 256 + tid;
      int row   = off16 >> 2;
      int colb  = (off16 & 3) << 4;
      const char* srcA = (const char*)(A  + (m0 + row) * K + k0) + colb;
      const char* srcB = (const char*)(BT + (n0 + row) * K + k0) + colb;
      async_lds16(srcA, sm +        (i * 256 + w * 64) * 16);
      async_lds16(srcB, sm + 8192 + (i * 256 + w * 64) * 16);
    }
    __syncthreads();
    bf16x8 af[4], bfr[4];
    #pragma unroll
    for (int t = 0; t < 4; ++t) {
      af[t]  = *(const bf16x8*)(sm +        ((wm * 64 + t * 16 + lr) * 32 + 8 * lg) * 2);
      bfr[t] = *(const bf16x8*)(sm + 8192 + ((wn * 64 + t * 16 + lr) * 32 + 8 * lg) * 2);
    }
    #pragma unroll
    for (int am = 0; am < 4; ++am)
      #pragma unroll
      for (int bn = 0; bn < 4; ++bn)
        acc[am][bn] = __builtin_amdgcn_mfma_f32_16x16x32_bf16(af[am], bfr[bn], acc[am][bn], 0, 0, 0);
  }
}

__global__ __launch_bounds__(256) void k_gemm_qkv(const bf16* __restrict__ A,
                                                  const bf16* __restrict__ BT,
                                                  bf16* __restrict__ Qb,
                                                  bf16* __restrict__ Kb,
                                                  bf16* __restrict__ VTb) {
  __shared__ char sm[16384];
  const int m0 = blockIdx.y * 128, n0 = blockIdx.x * 128;
  f32x4 acc[4][4];
  #pragma unroll
  for (int a = 0; a < 4; ++a)
    #pragma unroll
    for (int b = 0; b < 4; ++b) { f32x4 z = {0.f,0.f,0.f,0.f}; acc[a][b] = z; }
  gemm_tile(A, BT, 512, m0, n0, sm, acc);
  const int lane = threadIdx.x & 63, w = threadIdx.x >> 6;
  const int wm = w >> 1, wn = w & 1, lr = lane & 15, lg = lane >> 4;
  #pragma unroll
  for (int am = 0; am < 4; ++am)
    #pragma unroll
    for (int bn = 0; bn < 4; ++bn)
      #pragma unroll
      for (int r = 0; r < 4; ++r) {
        int m = m0 + wm * 64 + am * 16 + 4 * lg + r;
        int n = n0 + wn * 64 + bn * 16 + lr;
        int b = m >> 11, s = m & 2047;
        int which = n >> 9, h = (n >> 6) & 7, dk = n & 63;
        int bh = (b << 3) + h;
        bf16 v = (bf16)acc[am][bn][r];
        if (which == 0)      Qb[((bh << 11) + s) * 64 + dk] = v;
        else if (which == 1) Kb[((bh << 11) + s) * 64 + dk] = v;
        else                 VTb[((bh << 6) + dk) * 2048 + s] = v;
      }
}

__global__ __launch_bounds__(256) void k_gemm_out(const bf16* __restrict__ A,
                                                  const bf16* __restrict__ BT,
                                                  float* __restrict__ C) {
  __shared__ char sm[16384];
  const int m0 = blockIdx.y * 128, n0 = blockIdx.x * 128;
  f32x4 acc[4][4];
  #pragma unroll
  for (int a = 0; a < 4; ++a)
    #pragma unroll
    for (int b = 0; b < 4; ++b) { f32x4 z = {0.f,0.f,0.f,0.f}; acc[a][b] = z; }
  gemm_tile(A, BT, 512, m0, n0, sm, acc);
  const int lane = threadIdx.x & 63, w = threadIdx.x >> 6;
  const int wm = w >> 1, wn = w & 1, lr = lane & 15, lg = lane >> 4;
  #pragma unroll
  for (int am = 0; am < 4; ++am)
    #pragma unroll
    for (int bn = 0; bn < 4; ++bn)
      #pragma unroll
      for (int r = 0; r < 4; ++r) {
        int m = m0 + wm * 64 + am * 16 + 4 * lg + r;
        int n = n0 + wn * 64 + bn * 16 + lr;
        C[(m << 9) + n] = acc[am][bn][r];
      }
}

// ---------------- causal flash attention, swapped-operand, 2-wave KV-split ----------------
// 2 waves per block, both cover the SAME 32 Q-rows; wave w handles KV tiles
// t = w, w+2, ... (KVBLK=64). Each wave keeps private online-softmax state;
// at the end wave1 publishes (m,l,O^T) via LDS and wave0 combines + writes.
// QK^T: mfma(A=K, B=Q) -> S^T: lane holds scores of ONE q-row (q = lane&31).
// PV:   mfma(A=V^T, B=P) -> O^T: softmax state fully lane-local.
// C/D map (32x32): col = lane&31, row = (reg&3) + 8*(reg>>2) + 4*(lane>>5).

__global__ __launch_bounds__(128, 3) void k_attn3(const bf16* __restrict__ Qb,
                                                  const bf16* __restrict__ Kb,
                                                  const bf16* __restrict__ VTb,
                                                  bf16* __restrict__ Oc) {
  __shared__ float smO[32][64];   // [reg r][lane] from wave1
  __shared__ float smM[64], smL[64];
  const int tid = threadIdx.x, lane = tid & 63, wv = tid >> 6;
  const int l31 = lane & 31, hi = lane >> 5;
  const int bh = blockIdx.x, b = bh >> 3, h = bh & 7;
  const int qt = 63 - (int)blockIdx.y;           // longest-first dispatch
  const int q0 = qt << 5;
  const bf16* Qh = Qb  + ((size_t)bh << 17);
  const bf16* Kh = Kb  + ((size_t)bh << 17);
  const bf16* Vh = VTb + ((size_t)bh << 17);
  const float kSc = 0.125f * 1.44269504089f;     // 1/sqrt(64) * log2(e)

  bf16x8 qf[4];
  #pragma unroll
  for (int kd = 0; kd < 4; ++kd)
    qf[kd] = *(const bf16x8*)(Qh + ((q0 + l31) << 6) + kd * 16 + 8 * hi);

  f32x16 o0, o1;
  #pragma unroll
  for (int r = 0; r < 16; ++r) { o0[r] = 0.f; o1[r] = 0.f; }
  float m_run = -3e38f, lsum = 0.f;

  const int NT = (qt >> 1) + 1;                  // 64-wide KV tiles

  for (int t = wv; t < NT; t += 2) {
    const int tb = t << 6;
    // K fragments for this tile (8 loads; L2-resident, TLP hides latency)
    bf16x8 kf[8];
    #pragma unroll
    for (int j = 0; j < 2; ++j)
      #pragma unroll
      for (int kd = 0; kd < 4; ++kd)
        kf[j * 4 + kd] = *(const bf16x8*)(Kh + ((tb + (j << 5) + l31) << 6) + kd * 16 + 8 * hi);
    // V fragments (independent; consumed after softmax)
    bf16x8 vf[2][2][2];  // [half j][dvt][ks]
    #pragma unroll
    for (int j = 0; j < 2; ++j)
      #pragma unroll
      for (int dvt = 0; dvt < 2; ++dvt)
        #pragma unroll
        for (int ks = 0; ks < 2; ++ks)
          vf[j][dvt][ks] = *(const bf16x8*)(Vh + (((dvt << 5) + l31) << 11) + tb + (j << 5) + (ks << 4) + 8 * hi);

    // QK^T: two 32-col halves
    f32x16 sA, sB;
    #pragma unroll
    for (int r = 0; r < 16; ++r) { sA[r] = 0.f; sB[r] = 0.f; }
    __builtin_amdgcn_s_setprio(1);
    #pragma unroll
    for (int kd = 0; kd < 4; ++kd)
      sA = __builtin_amdgcn_mfma_f32_32x32x16_bf16(kf[kd], qf[kd], sA, 0, 0, 0);
    #pragma unroll
    for (int kd = 0; kd < 4; ++kd)
      sB = __builtin_amdgcn_mfma_f32_32x32x16_bf16(kf[4 + kd], qf[kd], sB, 0, 0, 0);
    __builtin_amdgcn_s_setprio(0);

    // causal mask (diagonal tile only)
    if (t == NT - 1) {
      const int sg = q0 + l31;
      #pragma unroll
      for (int r = 0; r < 16; ++r) {
        int rk = tb + (r & 3) + 8 * (r >> 2) + 4 * hi;
        sA[r] = (rk > sg)      ? -1e30f : sA[r];
        sB[r] = (rk + 32 > sg) ? -1e30f : sB[r];
      }
    }
    // row max: max3-shaped tree + one cross-half exchange
    float tv[16];
    #pragma unroll
    for (int r = 0; r < 16; ++r) tv[r] = fmaxf(sA[r], sB[r]);
    float t0 = fmaxf(fmaxf(tv[0], tv[1]), tv[2]);
    float t1 = fmaxf(fmaxf(tv[3], tv[4]), tv[5]);
    float t2 = fmaxf(fmaxf(tv[6], tv[7]), tv[8]);
    float t3 = fmaxf(fmaxf(tv[9], tv[10]), tv[11]);
    float t4 = fmaxf(fmaxf(tv[12], tv[13]), tv[14]);
    float t5 = fmaxf(fmaxf(t0, t1), t2);
    float t6 = fmaxf(fmaxf(t3, t4), tv[15]);
    float tmax = fmaxf(t5, t6);
    float tms = fmaxf(tmax, __shfl_xor(tmax, 32)) * kSc;
    // defer-max rescale (T13, THR=8 in exp2 domain)
    if (!__all(tms <= m_run + 8.f)) {
      float mn = fmaxf(m_run, tms);
      float fac = exp2f(m_run - mn);
      #pragma unroll
      for (int r = 0; r < 16; ++r) { o0[r] *= fac; o1[r] *= fac; }
      lsum *= fac;
      m_run = mn;
    }
    // P = exp2(s*kSc - m)
    float pA[16], pB[16];
    #pragma unroll
    for (int r = 0; r < 16; ++r) pA[r] = exp2f(fmaf(sA[r], kSc, -m_run));
    #pragma unroll
    for (int r = 0; r < 16; ++r) pB[r] = exp2f(fmaf(sB[r], kSc, -m_run));
    // row sum
    float sv[16];
    #pragma unroll
    for (int r = 0; r < 16; ++r) sv[r] = pA[r] + pB[r];
    #pragma unroll
    for (int st = 8; st > 0; st >>= 1)
      #pragma unroll
      for (int i = 0; i < 16; ++i) if (i < st) sv[i] += sv[i + st];
    lsum += sv[0] + __shfl_xor(sv[0], 32);

    // pack P -> bf16 pairs; permlane32_swap builds PV B-fragments in-register
    #pragma unroll
    for (int j = 0; j < 2; ++j) {
      const float* p = j ? pB : pA;
      u32 pk_[8];
      #pragma unroll
      for (int i = 0; i < 8; ++i) {
        unsigned short x = __builtin_bit_cast(unsigned short, (bf16)p[2 * i]);
        unsigned short y = __builtin_bit_cast(unsigned short, (bf16)p[2 * i + 1]);
        pk_[i] = (u32)x | ((u32)y << 16);
      }
      asm volatile("v_permlane32_swap_b32 %0, %1" : "+v"(pk_[0]), "+v"(pk_[2]));
      asm volatile("v_permlane32_swap_b32 %0, %1" : "+v"(pk_[1]), "+v"(pk_[3]));
      asm volatile("v_permlane32_swap_b32 %0, %1" : "+v"(pk_[4]), "+v"(pk_[6]));
      asm volatile("v_permlane32_swap_b32 %0, %1" : "+v"(pk_[5]), "+v"(pk_[7]));
      u32x4 w0 = { pk_[0], pk_[1], pk_[2], pk_[3] };
      u32x4 w1 = { pk_[4], pk_[5], pk_[6], pk_[7] };
      bf16x8 pb0 = __builtin_bit_cast(bf16x8, w0);
      bf16x8 pb1 = __builtin_bit_cast(bf16x8, w1);
      __builtin_amdgcn_s_setprio(1);
      o0 = __builtin_amdgcn_mfma_f32_32x32x16_bf16(vf[j][0][0], pb0, o0, 0, 0, 0);
      o0 = __builtin_amdgcn_mfma_f32_32x32x16_bf16(vf[j][0][1], pb1, o0, 0, 0, 0);
      o1 = __builtin_amdgcn_mfma_f32_32x32x16_bf16(vf[j][1][0], pb0, o1, 0, 0, 0);
      o1 = __builtin_amdgcn_mfma_f32_32x32x16_bf16(vf[j][1][1], pb1, o1, 0, 0, 0);
      __builtin_amdgcn_s_setprio(0);
    }
  }

  // ---- combine the two waves' partial states ----
  if (wv == 1) {
    #pragma unroll
    for (int r = 0; r < 16; ++r) {
      smO[r][lane]      = o0[r];
      smO[16 + r][lane] = o1[r];
    }
    smM[lane] = m_run;
    smL[lane] = lsum;
  }
  __syncthreads();
  if (wv == 0) {
    float m1 = smM[lane], l1 = smL[lane];
    float mm = fmaxf(m_run, m1);
    float f0 = exp2f(m_run - mm), f1 = exp2f(m1 - mm);
    float l  = lsum * f0 + l1 * f1;
    float rn = 1.f / l;
    const int sg = q0 + l31;
    bf16* Orow = Oc + (((size_t)((b << 11) + sg)) << 9) + (h << 6);
    #pragma unroll
    for (int g = 0; g < 4; ++g) {
      bf16x4 v0, v1;
      #pragma unroll
      for (int i = 0; i < 4; ++i) {
        v0[i] = (bf16)((o0[4 * g + i] * f0 + smO[4 * g + i][lane] * f1) * rn);
        v1[i] = (bf16)((o1[4 * g + i] * f0 + smO[16 + 4 * g + i][lane] * f1) * rn);
      }
      *(bf16x4*)(Orow + 4 * hi + 8 * g)      = v0;
      *(bf16x4*)(Orow + 32 + 4 * hi + 8 * g) = v1;
    }
  }
}

// ---------------- launch ----------------

extern "C" void kernel_launch(void* const* d_in, const int* in_sizes, int n_in,
                              void* d_out, int out_size, void* d_ws, size_t ws_size,
                              hipStream_t stream) {
  (void)in_sizes; (void)n_in; (void)out_size; (void)ws_size;
  const float* X  = (const float*)d_in[0];
  const float* Wq = (const float*)d_in[1];
  const float* Wk = (const float*)d_in[2];
  const float* Wv = (const float*)d_in[3];
  const float* Wo = (const float*)d_in[4];
  float* out = (float*)d_out;
  char* ws = (char*)d_ws;
  bf16* Xb   = (bf16*)(ws);
  bf16* Wqkv = (bf16*)(ws + 8388608);
  bf16* WoT  = (bf16*)(ws + 9961472);
  bf16* Qb   = (bf16*)(ws + 10485760);
  bf16* Kb   = (bf16*)(ws + 18874368);
  bf16* VTb  = (bf16*)(ws + 27262976);
  bf16* Oc   = (bf16*)(ws + 35651584);

  k_cvt_x<<<4096, 256, 0, stream>>>((const float4*)X, (bf16x4*)Xb);
  k_build_wqkv<<<3072, 256, 0, stream>>>(Wq, Wk, Wv, Wqkv);
  k_build_wo<<<1024, 256, 0, stream>>>(Wo, WoT);
  k_gemm_qkv<<<dim3(12, 64), 256, 0, stream>>>(Xb, Wqkv, Qb, Kb, VTb);
  k_attn3<<<dim3(32, 64), 128, 0, stream>>>(Qb, Kb, VTb, Oc);
  k_gemm_out<<<dim3(4, 64), 256, 0, stream>>>(Oc, WoT, out);
}